// Round 10
// baseline (299.781 us; speedup 1.0000x reference)
//
#include <hip/hip_runtime.h>
#include <hip/hip_bf16.h>

#define LL 9216            // 96*96
#define TOT 36864          // 4*LL
#define CHK 144
#define NSEG 144
#define EPS_N 5e-5f

typedef __bf16 bf16x8 __attribute__((ext_vector_type(8)));
typedef float f32x4 __attribute__((ext_vector_type(4)));

__device__ __forceinline__ float dot4(float4 a, float4 b) {
    return a.x*b.x + a.y*b.y + a.z*b.z + a.w*b.w;
}
__device__ __forceinline__ unsigned short f2bf(float f) {
    __hip_bfloat16 h = __float2bfloat16(f);
    return *reinterpret_cast<unsigned short*>(&h);
}
__device__ __forceinline__ float bf2f(unsigned short u) {
    return __uint_as_float(((unsigned int)u) << 16);
}

// ---------------- K1: xe conv (uniform global weights) + LSH codes + w-prep ------
// blocks 0..287: conv 8x8 tile + codes; blocks 288..575: weight prep.
// R7-proven variant: 46 KB LDS -> 3 blocks/CU; weight reads are wave-uniform
// (readfirstlane -> scalar loads), x reads from LDS.
__global__ __launch_bounds__(256) void k_front(
    const float* __restrict__ x, const float* __restrict__ wm,
    const float* __restrict__ bm, const float* __restrict__ rot,
    float* __restrict__ xe, float* __restrict__ xn,
    unsigned char* __restrict__ codes,
    const float* __restrict__ fc1w, const float* __restrict__ fc2w,
    const float* __restrict__ wa, const float* __restrict__ wf,
    unsigned short* __restrict__ w1bf, unsigned short* __restrict__ w2bf,
    unsigned short* __restrict__ wpack)
{
    int tid = threadIdx.x;
    if (blockIdx.x >= 288) {   // ---- weight prep ----
        int i = (blockIdx.x - 288) * 256 + tid;
        if (i < 144 * 64) w1bf[i] = f2bf(fc1w[i]);
        if (i < 144 * 160) {
            int r = i / 160, c = i - r * 160;
            w2bf[i] = (c < 144) ? f2bf(fc2w[r * 144 + c]) : 0;
        }
        if (i < 128 * 576) {
            int o = i / 576, kk = i - o * 576;
            int dydx = kk >> 6, c = kk & 63;
            const float* src = (o < 64) ? wa : wf;
            wpack[i] = f2bf(src[(o & 63) * 576 + c * 9 + dydx]);
        }
        return;
    }
    __shared__ float xl[6400];       // [64][10][10] halo tile (25.6 KB)
    __shared__ float rotT[4096];     // [h*64+i][16]          (16 KB)
    __shared__ float xsp[64 * 20];   // [pos][ch pad20]       (5 KB)
    int b = blockIdx.x;
    int n = b / 144, tile = b % 144;
    int ty0 = (tile / 12) * 8, tx0 = (tile % 12) * 8;
    for (int li = tid; li < 6400; li += 256) {
        int c = li / 100, s = li % 100;
        int yy = s / 10, xx = s % 10;
        int gy = ty0 + yy - 1, gx = tx0 + xx - 1;
        float v = 0.f;
        if ((unsigned)gy < 96u && (unsigned)gx < 96u)
            v = x[((n * 64 + c) * 96 + gy) * 96 + gx];
        xl[li] = v;
    }
    for (int e = tid; e < 4096; e += 256) {
        int f = e >> 8, r = e & 255;
        rotT[r * 16 + f] = rot[f * 256 + r];   // rot is (16,4,64)
    }
    __syncthreads();
    int p = tid & 63, og = tid >> 6;
    int row = p >> 3, col = p & 7;
    int ogs = __builtin_amdgcn_readfirstlane(og);   // wave-uniform -> s_load path
    const float* wb = wm + (size_t)ogs * 4 * 576;
    float acc0 = 0.f, acc1 = 0.f, acc2 = 0.f, acc3 = 0.f;
    for (int c = 0; c < 64; ++c) {
        float xp[9];
        int base = c * 100 + row * 10 + col;
        #pragma unroll
        for (int dy = 0; dy < 3; ++dy)
            #pragma unroll
            for (int dx = 0; dx < 3; ++dx)
                xp[dy * 3 + dx] = xl[base + dy * 10 + dx];
        const float* w0 = wb + c * 9;
        #pragma unroll
        for (int u = 0; u < 9; ++u) {
            acc0 += w0[u]        * xp[u];
            acc1 += w0[576 + u]  * xp[u];
            acc2 += w0[1152 + u] * xp[u];
            acc3 += w0[1728 + u] * xp[u];
        }
    }
    int o = ogs * 4;
    float v0 = acc0 + bm[o + 0]; v0 = v0 > 0.f ? v0 : 0.f;
    float v1 = acc1 + bm[o + 1]; v1 = v1 > 0.f ? v1 : 0.f;
    float v2 = acc2 + bm[o + 2]; v2 = v2 > 0.f ? v2 : 0.f;
    float v3 = acc3 + bm[o + 3]; v3 = v3 > 0.f ? v3 : 0.f;
    size_t t = (size_t)n * LL + (ty0 + row) * 96 + tx0 + col;
    float4 vv = make_float4(v0, v1, v2, v3);
    *(float4*)(xe + t * 16 + o) = vv;
    *(float4*)(xsp + p * 20 + o) = vv;
    __syncthreads();
    // ---- codes phase: thread = (pos = tid&63, h = tid>>6) ----
    int pos = tid & 63, h = tid >> 6;
    int prow = pos >> 3, pcol = pos & 7;
    size_t tc = (size_t)n * LL + (ty0 + prow) * 96 + tx0 + pcol;
    float4 q0 = *(float4*)(xsp + pos * 20 + 0);
    float4 q1 = *(float4*)(xsp + pos * 20 + 4);
    float4 q2 = *(float4*)(xsp + pos * 20 + 8);
    float4 q3 = *(float4*)(xsp + pos * 20 + 12);
    if (h == 0) {
        float nn = dot4(q0,q0) + dot4(q1,q1) + dot4(q2,q2) + dot4(q3,q3);
        float s = fmaxf(sqrtf(nn), EPS_N);
        float inv = 1.f / s;
        float4* dst = (float4*)(xn + tc * 16);
        dst[0] = make_float4(q0.x*inv, q0.y*inv, q0.z*inv, q0.w*inv);
        dst[1] = make_float4(q1.x*inv, q1.y*inv, q1.z*inv, q1.w*inv);
        dst[2] = make_float4(q2.x*inv, q2.y*inv, q2.z*inv, q2.w*inv);
        dst[3] = make_float4(q3.x*inv, q3.y*inv, q3.z*inv, q3.w*inv);
    }
    float best = -1e30f; int bi = 0;
    const float* rp = rotT + h * 1024;
    for (int i = 0; i < 64; ++i) {
        const float4* r4 = (const float4*)(rp + i * 16);
        float v = dot4(q0, r4[0]) + dot4(q1, r4[1]) + dot4(q2, r4[2]) + dot4(q3, r4[3]);
        if (v > best) { best = v; bi = i; }   // strict > = first max (jnp.argmax)
    }
    codes[(size_t)n * TOT + h * LL + (tc - (size_t)n * LL)] = (unsigned char)(h * 64 + bi);
}

// ---------------- K2: ye/fe conv bf16 MFMA + fused fc1/relu/fc2 + fused hist -----
// blocks 0..383: conv+fc strip; blocks 384..671: sort histogram.
__global__ __launch_bounds__(256) void k_convbf_fc(
    const float* __restrict__ x, const unsigned short* __restrict__ wpack,
    const float* __restrict__ ba, const float* __restrict__ bfb,
    const unsigned short* __restrict__ w1bf, const float* __restrict__ fc1_b,
    const unsigned short* __restrict__ w2bf, const float* __restrict__ fc2_b,
    unsigned short* __restrict__ yeb, unsigned short* __restrict__ re2b,
    const unsigned char* __restrict__ codes, int* __restrict__ hist)
{
    __shared__ unsigned short xt[3 * 50 * 72];   // input halo strip, ch-inner
    __shared__ unsigned short fet[48 * 72];      // fe tile [pos][ch]
    __shared__ unsigned short hb [48 * 168];     // hid [pos][m pad160]
    __shared__ int lh[256];
    int tid = threadIdx.x;
    if (blockIdx.x >= 384) {   // ---- histogram branch ----
        int b2 = blockIdx.x - 384;
        int n = b2 / NSEG, seg = b2 % NSEG;
        lh[tid] = 0;
        __syncthreads();
        int code = codes[(size_t)n * TOT + seg * 256 + tid];
        atomicAdd(&lh[code], 1);
        __syncthreads();
        hist[((size_t)n * 256 + tid) * NSEG + seg] = lh[tid];
        return;
    }
    int b = blockIdx.x;
    int n = b / 192, rem = b % 192;
    int y = rem >> 1, strip = rem & 1;
    int x0 = strip * 48;
    for (int e = tid; e < 9600; e += 256) {
        int r = e / 3200, r2 = e - r * 3200;
        int c = r2 / 50, j = r2 - c * 50;
        int gy = y - 1 + r, gx = x0 - 1 + j;
        float v = 0.f;
        if ((unsigned)gy < 96u && (unsigned)gx < 96u)
            v = x[((n * 64 + c) * 96 + gy) * 96 + gx];
        xt[(r * 50 + j) * 72 + c] = f2bf(v);
    }
    for (int e = tid; e < 384; e += 256) {       // hb K-pad zero (cols 144..159)
        int r = e >> 3, pq = e & 7;
        *(unsigned int*)(hb + r * 168 + 144 + pq * 2) = 0;
    }
    __syncthreads();
    int wave = tid >> 6, lane = tid & 63;
    int n16 = lane & 15, quad = lane >> 4;
    f32x4 acc[2][3];
    #pragma unroll
    for (int mi = 0; mi < 2; ++mi)
        #pragma unroll
        for (int nt = 0; nt < 3; ++nt) acc[mi][nt] = (f32x4){0.f, 0.f, 0.f, 0.f};
    #pragma unroll
    for (int s = 0; s < 18; ++s) {
        int dydx = s >> 1, half = s & 1;
        int dy = dydx / 3, dxm = dydx - dy * 3;
        bf16x8 B[3];
        #pragma unroll
        for (int nt = 0; nt < 3; ++nt) {
            int j = nt * 16 + n16 + dxm;
            B[nt] = *(bf16x8*)(xt + (dy * 50 + j) * 72 + half * 32 + quad * 8);
        }
        #pragma unroll
        for (int mi = 0; mi < 2; ++mi) {
            int o = (wave * 2 + mi) * 16 + n16;
            bf16x8 A = *(const bf16x8*)(wpack + o * 576 + dydx * 64 + half * 32 + quad * 8);
            #pragma unroll
            for (int nt = 0; nt < 3; ++nt)
                acc[mi][nt] = __builtin_amdgcn_mfma_f32_16x16x32_bf16(A, B[nt], acc[mi][nt], 0, 0, 0);
        }
    }
    #pragma unroll
    for (int mi = 0; mi < 2; ++mi) {
        int mt = wave * 2 + mi;
        int obase = mt * 16 + quad * 4;          // 0..124, multiple of 4
        float4 b4 = (mt < 4) ? *(const float4*)(ba + obase)
                             : *(const float4*)(bfb + obase - 64);
        #pragma unroll
        for (int nt = 0; nt < 3; ++nt) {
            int j = nt * 16 + n16;               // local position 0..47
            unsigned short pk[4];
            float v0 = acc[mi][nt][0] + b4.x; pk[0] = f2bf(v0 > 0.f ? v0 : 0.f);
            float v1 = acc[mi][nt][1] + b4.y; pk[1] = f2bf(v1 > 0.f ? v1 : 0.f);
            float v2 = acc[mi][nt][2] + b4.z; pk[2] = f2bf(v2 > 0.f ? v2 : 0.f);
            float v3 = acc[mi][nt][3] + b4.w; pk[3] = f2bf(v3 > 0.f ? v3 : 0.f);
            if (mt < 4) {
                size_t t = (size_t)n * LL + y * 96 + x0 + j;
                *(uint2*)(yeb + t * 64 + obase) = *(uint2*)pk;
            } else {
                *(uint2*)(fet + j * 72 + (obase - 64)) = *(uint2*)pk;
            }
        }
    }
    __syncthreads();
    size_t R0 = (size_t)n * LL + y * 96 + x0;
    // GEMM1: hid = relu(fe @ w1^T + b1)
    for (int nt = wave; nt < 9; nt += 4) {
        int bn = nt * 16 + n16;
        bf16x8 b0 = *(const bf16x8*)(w1bf + bn * 64 + quad * 8);
        bf16x8 b1 = *(const bf16x8*)(w1bf + bn * 64 + 32 + quad * 8);
        float bb = fc1_b[bn];
        #pragma unroll
        for (int m = 0; m < 3; ++m) {
            int arow = m * 16 + n16;
            bf16x8 a0 = *(bf16x8*)(fet + arow * 72 + quad * 8);
            bf16x8 a1 = *(bf16x8*)(fet + arow * 72 + 32 + quad * 8);
            f32x4 c2 = {0.f, 0.f, 0.f, 0.f};
            c2 = __builtin_amdgcn_mfma_f32_16x16x32_bf16(a0, b0, c2, 0, 0, 0);
            c2 = __builtin_amdgcn_mfma_f32_16x16x32_bf16(a1, b1, c2, 0, 0, 0);
            #pragma unroll
            for (int r = 0; r < 4; ++r) {
                float v = c2[r] + bb;
                hb[(m * 16 + quad * 4 + r) * 168 + bn] = f2bf(v > 0.f ? v : 0.f);
            }
        }
    }
    __syncthreads();
    // GEMM2: re2 = hid @ w2^T + b2 (K=160)
    for (int nt = wave; nt < 9; nt += 4) {
        int bn = nt * 16 + n16;
        bf16x8 wv2[5];
        #pragma unroll
        for (int kk = 0; kk < 5; ++kk)
            wv2[kk] = *(const bf16x8*)(w2bf + bn * 160 + kk * 32 + quad * 8);
        float bb = fc2_b[bn];
        #pragma unroll
        for (int m = 0; m < 3; ++m) {
            int arow = m * 16 + n16;
            f32x4 c2 = {0.f, 0.f, 0.f, 0.f};
            #pragma unroll
            for (int kk = 0; kk < 5; ++kk) {
                bf16x8 a = *(bf16x8*)(hb + arow * 168 + kk * 32 + quad * 8);
                c2 = __builtin_amdgcn_mfma_f32_16x16x32_bf16(a, wv2[kk], c2, 0, 0, 0);
            }
            #pragma unroll
            for (int r = 0; r < 4; ++r)
                re2b[(R0 + m * 16 + quad * 4 + r) * 144 + bn] = f2bf(c2[r] + bb);
        }
    }
}

// ---------------- K3: counting sort scan + place --------------------------------
__global__ void k_scan(int* __restrict__ hist)
{
    __shared__ int sc[256];
    int n = blockIdx.x, bin = threadIdx.x;
    int* hp = hist + ((size_t)n * 256 + bin) * NSEG;
    int4 buf[36];
    int4* hp4 = (int4*)hp;
    #pragma unroll
    for (int q = 0; q < 36; ++q) buf[q] = hp4[q];
    int running = 0;
    #pragma unroll
    for (int q = 0; q < 36; ++q) {
        int t0 = buf[q].x; buf[q].x = running; running += t0;
        int t1 = buf[q].y; buf[q].y = running; running += t1;
        int t2 = buf[q].z; buf[q].z = running; running += t2;
        int t3 = buf[q].w; buf[q].w = running; running += t3;
    }
    sc[bin] = running;
    __syncthreads();
    for (int off = 1; off < 256; off <<= 1) {
        int v = sc[bin];
        int u = (bin >= off) ? sc[bin - off] : 0;
        __syncthreads();
        sc[bin] = v + u;
        __syncthreads();
    }
    int bs = sc[bin] - running;   // exclusive prefix over bins
    #pragma unroll
    for (int q = 0; q < 36; ++q) {
        buf[q].x += bs; buf[q].y += bs; buf[q].z += bs; buf[q].w += bs;
        hp4[q] = buf[q];
    }
}

__global__ __launch_bounds__(256) void k_place(
    const unsigned char* __restrict__ codes, const int* __restrict__ hist,
    int* __restrict__ idx)
{
    __shared__ unsigned char cl[256];
    int b = blockIdx.x, n = b / NSEG, seg = b % NSEG;
    int tid = threadIdx.x;
    int my = codes[(size_t)n * TOT + seg * 256 + tid];
    cl[tid] = (unsigned char)my;
    __syncthreads();
    int rank = 0;
    for (int j = 0; j < tid; ++j) rank += (cl[j] == my);
    int pos = hist[((size_t)n * 256 + my) * NSEG + seg] + rank;
    idx[(size_t)n * TOT + pos] = seg * 256 + tid;
}

// ---------------- K4: bucketed attention, QUERY-SPLIT x3, 2-barrier pipeline -----
// grid 1536: b = chunk*3 + qs; block owns queries [qs*48, qs*48+48) vs all 432 keys.
// Outputs identical to unsplit version (complete softmax per query; no merge).
__global__ __launch_bounds__(256, 4) void k_attn(
    const float* __restrict__ xe, const float* __restrict__ xn,
    const unsigned short* __restrict__ yeb, const unsigned short* __restrict__ re2b,
    const int* __restrict__ idx,
    unsigned short* __restrict__ ret, float* __restrict__ bsc)
{
    __shared__ float xs_s[48 * 16];            // our query rows (f32)
    __shared__ float xnc[2][48 * 20];          // normalized key tile (f32), dbuf
    __shared__ unsigned short Pb[48 * 72];     // probs bf16 [i][jpad], cols 48..63 = 0
    __shared__ unsigned short yat[2][64 * 72]; // values^T bf16 [c][jpad], dbuf
    __shared__ int   t_arr[432];
    __shared__ float l_sh[48], alpha_sh[48];

    int b = blockIdx.x;
    int chunk = b / 3, qs = b - chunk * 3;     // qs fastest: siblings share L2 tiles
    int n = chunk >> 8, rem = chunk & 255;
    int h = rem >> 6, k = rem & 63;
    int q0r = qs * 48;                         // our query-row base (0/48/96)
    int tid = threadIdx.x;

    for (int r = tid; r < 432; r += 256) {
        int region = r / 144, i = r - region * 144;
        int dk = (region == 0) ? 0 : (region == 1 ? -1 : 1);
        int ck = (k + dk + 64) & 63;
        t_arr[r] = idx[(size_t)n * TOT + h * LL + ck * CHK + i] - h * LL;
    }
    for (int e = tid; e < 768; e += 256)               // Pb K-pad zero
        Pb[(e >> 4) * 72 + 48 + (e & 15)] = 0;
    for (int e = tid; e < 2048; e += 256) {            // yat K-pad zero (both bufs)
        int bb2 = e >> 10, r2 = (e >> 4) & 63;
        yat[bb2][r2 * 72 + 48 + (e & 15)] = 0;
    }
    __syncthreads();                                   // t_arr ready
    int si = tid >> 4, tj = tid & 15;          // QK grid: rows si*3.., cols tj*3..
    int lane = tid & 63, wv = tid >> 6;
    int n16 = lane & 15, quad = lane >> 4;     // MFMA lane coords
    if (tid < 192) {                           // 48 query rows x 4 float4
        int r = tid >> 2, q = tid & 3;
        *(float4*)(xs_s + r * 16 + q * 4) =
            *(const float4*)(xe + ((size_t)n * LL + t_arr[q0r + r]) * 16 + q * 4);
    }
    // stage tile 0 into buf 0
    {
        #pragma unroll
        for (int q = 0; q < 6; ++q) {
            int e = tid + q * 256;
            int j = e >> 5, c2 = e & 31;
            unsigned int v = *(const unsigned int*)(yeb + ((size_t)n * LL + t_arr[j]) * 64 + c2 * 2);
            yat[0][(c2 * 2 + 0) * 72 + j] = (unsigned short)(v & 0xffff);
            yat[0][(c2 * 2 + 1) * 72 + j] = (unsigned short)(v >> 16);
        }
        if (tid < 192) {
            int j = tid >> 2, q = tid & 3;
            *(float4*)(&xnc[0][j * 20 + q * 4]) =
                *(const float4*)(xn + ((size_t)n * LL + t_arr[j]) * 16 + q * 4);
        }
    }
    // preload tile-0 fc scores: fc_raw[i][j] = re2[t_j][i], i = q0r + si*3 + u
    unsigned short fcvA[9], fcvB[9];
    #pragma unroll
    for (int v = 0; v < 3; ++v) {
        const unsigned short* fp = re2b + ((size_t)n * LL + t_arr[tj * 3 + v]) * 144 + q0r + si * 3;
        #pragma unroll
        for (int u = 0; u < 3; ++u) fcvA[v * 3 + u] = fp[u];
    }
    f32x4 acc[3];
    float rm[3], rl[3];
    #pragma unroll
    for (int q = 0; q < 3; ++q) {
        acc[q] = (f32x4){0.f, 0.f, 0.f, 0.f};
        rm[q] = -1e30f; rl[q] = 0.f;
    }
    __syncthreads();                           // tile-0 staging visible

    for (int T = 0; T < 9; ++T) {
        int cur = T & 1, nxt = cur ^ 1;
        int r0 = T * 48;
        // ---- issue next-tile staging loads into registers ----
        unsigned int syv[6];
        float4 sxn;
        if (T < 8) {
            int r1 = r0 + 48;
            #pragma unroll
            for (int q = 0; q < 6; ++q) {
                int e = tid + q * 256;
                int j = e >> 5, c2 = e & 31;
                syv[q] = *(const unsigned int*)(yeb + ((size_t)n * LL + t_arr[r1 + j]) * 64 + c2 * 2);
            }
            if (tid < 192) {
                int j = tid >> 2, q = tid & 3;
                sxn = *(const float4*)(xn + ((size_t)n * LL + t_arr[r1 + j]) * 16 + q * 4);
            }
            #pragma unroll
            for (int v = 0; v < 3; ++v) {
                const unsigned short* fp =
                    re2b + ((size_t)n * LL + t_arr[r1 + tj * 3 + v]) * 144 + q0r + si * 3;
                #pragma unroll
                for (int u = 0; u < 3; ++u) fcvB[v * 3 + u] = fp[u];
            }
        }
        // ---- QK + fused online softmax (16-lane groups own 3 rows each) ----
        {
            float4 xnr[3][4];
            #pragma unroll
            for (int v = 0; v < 3; ++v)
                #pragma unroll
                for (int q = 0; q < 4; ++q)
                    xnr[v][q] = *(const float4*)(&xnc[cur][(tj * 3 + v) * 20 + q * 4]);
            #pragma unroll
            for (int u = 0; u < 3; ++u) {
                int i = si * 3 + u;            // local row 0..47
                const float4* xr = (const float4*)(xs_s + i * 16);
                float4 x0 = xr[0], x1 = xr[1], x2 = xr[2], x3 = xr[3];
                float rv[3];
                #pragma unroll
                for (int v = 0; v < 3; ++v) {
                    float d = dot4(x0, xnr[v][0]) + dot4(x1, xnr[v][1])
                            + dot4(x2, xnr[v][2]) + dot4(x3, xnr[v][3]);
                    rv[v] = bf2f(fcvA[v * 3 + u]) + d;
                }
                float mm = fmaxf(fmaxf(rv[0], rv[1]), rv[2]);
                mm = fmaxf(mm, __shfl_xor(mm, 1, 16));
                mm = fmaxf(mm, __shfl_xor(mm, 2, 16));
                mm = fmaxf(mm, __shfl_xor(mm, 4, 16));
                mm = fmaxf(mm, __shfl_xor(mm, 8, 16));
                float mn = fmaxf(rm[u], mm);
                float a = __expf(rm[u] - mn);
                float s0 = __expf(rv[0] - mn), s1 = __expf(rv[1] - mn), s2 = __expf(rv[2] - mn);
                float ss = s0 + s1 + s2;
                ss += __shfl_xor(ss, 1, 16);
                ss += __shfl_xor(ss, 2, 16);
                ss += __shfl_xor(ss, 4, 16);
                ss += __shfl_xor(ss, 8, 16);
                rl[u] = rl[u] * a + ss;
                rm[u] = mn;
                if (tj == 0) { alpha_sh[i] = a; l_sh[i] = rl[u]; }
                Pb[i * 72 + tj * 3 + 0] = f2bf(s0);
                Pb[i * 72 + tj * 3 + 1] = f2bf(s1);
                Pb[i * 72 + tj * 3 + 2] = f2bf(s2);
            }
        }
        __syncthreads();   // (A) Pb/alpha ready for PV; prev-PV done with yat[nxt]
        // ---- spill staged regs to LDS[nxt]; rotate fcv ----
        if (T < 8) {
            #pragma unroll
            for (int q = 0; q < 6; ++q) {
                int e = tid + q * 256;
                int j = e >> 5, c2 = e & 31;
                yat[nxt][(c2 * 2 + 0) * 72 + j] = (unsigned short)(syv[q] & 0xffff);
                yat[nxt][(c2 * 2 + 1) * 72 + j] = (unsigned short)(syv[q] >> 16);
            }
            if (tid < 192) {
                int j = tid >> 2, q = tid & 3;
                *(float4*)(&xnc[nxt][j * 20 + q * 4]) = sxn;
            }
            #pragma unroll
            for (int q = 0; q < 9; ++q) fcvA[q] = fcvB[q];
        }
        // ---- PV via MFMA: wave wv owns c-tile wv; 3 row-tiles ----
        {
            #pragma unroll
            for (int mt = 0; mt < 3; ++mt) {
                float4 al = *(const float4*)(alpha_sh + mt * 16 + quad * 4);
                acc[mt][0] *= al.x; acc[mt][1] *= al.y;
                acc[mt][2] *= al.z; acc[mt][3] *= al.w;
            }
            #pragma unroll
            for (int kk = 0; kk < 2; ++kk) {
                bf16x8 B = *(bf16x8*)(yat[cur] + (wv * 16 + n16) * 72 + kk * 32 + quad * 8);
                #pragma unroll
                for (int mt = 0; mt < 3; ++mt) {
                    bf16x8 A = *(bf16x8*)(Pb + (mt * 16 + n16) * 72 + kk * 32 + quad * 8);
                    acc[mt] = __builtin_amdgcn_mfma_f32_16x16x32_bf16(A, B, acc[mt], 0, 0, 0);
                }
            }
        }
        __syncthreads();   // (B) Pb free for next QK; xnc/yat[nxt] visible
    }
    // ---- epilogue: bsc from registers; normalize + scatter ret (bf16) ----
    if (tj == 0) {
        #pragma unroll
        for (int u = 0; u < 3; ++u) {
            int i = si * 3 + u;
            bsc[((size_t)n * 4 + h) * LL + t_arr[q0r + i]] = rm[u] + __logf(rl[u]);
        }
    }
    size_t obase = ((size_t)n * 4 + h) * LL;
    #pragma unroll
    for (int mt = 0; mt < 3; ++mt) {
        float4 l4 = *(const float4*)(l_sh + mt * 16 + quad * 4);
        int4 t4 = *(const int4*)(t_arr + q0r + mt * 16 + quad * 4);
        ret[(obase + t4.x) * 64 + wv * 16 + n16] = f2bf(acc[mt][0] * (1.f / l4.x));
        ret[(obase + t4.y) * 64 + wv * 16 + n16] = f2bf(acc[mt][1] * (1.f / l4.y));
        ret[(obase + t4.z) * 64 + wv * 16 + n16] = f2bf(acc[mt][2] * (1.f / l4.z));
        ret[(obase + t4.w) * 64 + wv * 16 + n16] = f2bf(acc[mt][3] * (1.f / l4.w));
    }
}

// ---------------- K5: softmax over rounds + residual, NCHW output ----------------
__global__ __launch_bounds__(256) void k_final(
    const unsigned short* __restrict__ ret, const float* __restrict__ bsc,
    const float* __restrict__ x, float* __restrict__ out)
{
    __shared__ float pr[4][64];
    __shared__ float accl[64 * 65];
    int b = blockIdx.x, n = b / 144;
    int t0 = (b % 144) * 64;
    int tid = threadIdx.x;
    if (tid < 64) {
        int t = t0 + tid;
        float b0 = bsc[((size_t)n*4 + 0)*LL + t];
        float b1 = bsc[((size_t)n*4 + 1)*LL + t];
        float b2 = bsc[((size_t)n*4 + 2)*LL + t];
        float b3 = bsc[((size_t)n*4 + 3)*LL + t];
        float mx = fmaxf(fmaxf(b0, b1), fmaxf(b2, b3));
        float e0 = __expf(b0-mx), e1 = __expf(b1-mx), e2 = __expf(b2-mx), e3 = __expf(b3-mx);
        float inv = 1.f / (e0 + e1 + e2 + e3);
        pr[0][tid] = e0*inv; pr[1][tid] = e1*inv; pr[2][tid] = e2*inv; pr[3][tid] = e3*inv;
    }
    __syncthreads();
    int cc = tid & 63, tt4 = tid >> 6;
    #pragma unroll
    for (int q = 0; q < 16; ++q) {
        int tt = tt4 + 4*q;
        int t = t0 + tt;
        float v = 0.f;
        #pragma unroll
        for (int h2 = 0; h2 < 4; ++h2)
            v += bf2f(ret[(((size_t)n*4 + h2)*LL + t)*64 + cc]) * pr[h2][tt];
        accl[cc*65 + tt] = v;
    }
    __syncthreads();
    int tt = tid & 63, c4 = tid >> 6;
    #pragma unroll
    for (int q = 0; q < 16; ++q) {
        int ch = c4 + 4*q;
        size_t o = ((size_t)n*64 + ch)*LL + t0 + tt;
        out[o] = accl[ch*65 + tt] + x[o];   // RES_SCALE = 1.0
    }
}

// ---------------- launcher ----------------
extern "C" void kernel_launch(void* const* d_in, const int* in_sizes, int n_in,
                              void* d_out, int out_size, void* d_ws, size_t ws_size,
                              hipStream_t stream)
{
    const float* x    = (const float*)d_in[0];
    const float* rot  = (const float*)d_in[1];
    const float* wm   = (const float*)d_in[2];
    const float* bm   = (const float*)d_in[3];
    const float* wa   = (const float*)d_in[4];
    const float* ba   = (const float*)d_in[5];
    const float* wf   = (const float*)d_in[6];
    const float* bf   = (const float*)d_in[7];
    const float* fc1w = (const float*)d_in[8];
    const float* fc1b = (const float*)d_in[9];
    const float* fc2w = (const float*)d_in[10];
    const float* fc2b = (const float*)d_in[11];
    float* out = (float*)d_out;

    char* ws = (char*)d_ws;
    float* xe            = (float*)(ws + 0);                  // 2*9216*16 f32
    unsigned short* yeb  = (unsigned short*)(ws + 1179648);   // 2*9216*64 bf16
    float* xn            = (float*)(ws + 3538944);            // 2*9216*16 f32
    unsigned short* re2b = (unsigned short*)(ws + 4718592);   // 2*9216*144 bf16
    unsigned short* w1bf = (unsigned short*)(ws + 10027008);  // 144*64 bf16
    unsigned short* w2bf = (unsigned short*)(ws + 10045440);  // 144*160 bf16
    unsigned short* wpak = (unsigned short*)(ws + 10091520);  // 128*576 bf16
    unsigned char* codes = (unsigned char*)(ws + 10238976);   // 2*36864 u8
    int* hist            = (int*)(ws + 10312704);             // 2*256*144 i32
    int* idxb            = (int*)(ws + 10607616);             // 2*36864 i32
    unsigned short* retb = (unsigned short*)(ws + 10902528);  // 2*4*9216*64 bf16
    float* bscb          = (float*)(ws + 20339712);           // 2*4*9216 f32 (end 20,634,624)

    k_front    <<<576, 256, 0, stream>>>(x, wm, bm, rot, xe, xn, codes,
                                         fc1w, fc2w, wa, wf, w1bf, w2bf, wpak);
    k_convbf_fc<<<672, 256, 0, stream>>>(x, wpak, ba, bf, w1bf, fc1b, w2bf, fc2b,
                                         yeb, re2b, codes, hist);
    k_scan     <<<2,   256, 0, stream>>>(hist);
    k_place    <<<288, 256, 0, stream>>>(codes, hist, idxb);
    k_attn     <<<1536, 256, 0, stream>>>(xe, xn, yeb, re2b, idxb, retb, bscb);
    k_final    <<<288, 256, 0, stream>>>(retb, bscb, x, out);
}

// Round 11
// 250.249 us; speedup vs baseline: 1.1979x; 1.1979x over previous
//
#include <hip/hip_runtime.h>
#include <hip/hip_bf16.h>

#define LL 9216            // 96*96
#define TOT 36864          // 4*LL
#define CHK 144
#define NSEG 144
#define EPS_N 5e-5f

typedef __bf16 bf16x8 __attribute__((ext_vector_type(8)));
typedef float f32x4 __attribute__((ext_vector_type(4)));

__device__ __forceinline__ float dot4(float4 a, float4 b) {
    return a.x*b.x + a.y*b.y + a.z*b.z + a.w*b.w;
}
__device__ __forceinline__ unsigned short f2bf(float f) {
    __hip_bfloat16 h = __float2bfloat16(f);
    return *reinterpret_cast<unsigned short*>(&h);
}
__device__ __forceinline__ float bf2f(unsigned short u) {
    return __uint_as_float(((unsigned int)u) << 16);
}

// ---------------- K1: xe conv (uniform global weights) + LSH codes + w-prep ------
// blocks 0..287: conv 8x8 tile + codes; blocks 288..575: weight prep. 46 KB LDS.
__global__ __launch_bounds__(256) void k_front(
    const float* __restrict__ x, const float* __restrict__ wm,
    const float* __restrict__ bm, const float* __restrict__ rot,
    float* __restrict__ xe, float* __restrict__ xn,
    unsigned char* __restrict__ codes,
    const float* __restrict__ fc1w, const float* __restrict__ fc2w,
    const float* __restrict__ wa, const float* __restrict__ wf,
    unsigned short* __restrict__ w1bf, unsigned short* __restrict__ w2bf,
    unsigned short* __restrict__ wpack)
{
    int tid = threadIdx.x;
    if (blockIdx.x >= 288) {   // ---- weight prep ----
        int i = (blockIdx.x - 288) * 256 + tid;
        if (i < 144 * 64) w1bf[i] = f2bf(fc1w[i]);
        if (i < 144 * 160) {
            int r = i / 160, c = i - r * 160;
            w2bf[i] = (c < 144) ? f2bf(fc2w[r * 144 + c]) : 0;
        }
        if (i < 128 * 576) {
            int o = i / 576, kk = i - o * 576;
            int dydx = kk >> 6, c = kk & 63;
            const float* src = (o < 64) ? wa : wf;
            wpack[i] = f2bf(src[(o & 63) * 576 + c * 9 + dydx]);
        }
        return;
    }
    __shared__ float xl[6400];       // [64][10][10] halo tile (25.6 KB)
    __shared__ float rotT[4096];     // [h*64+i][16]          (16 KB)
    __shared__ float xsp[64 * 20];   // [pos][ch pad20]       (5 KB)
    int b = blockIdx.x;
    int n = b / 144, tile = b % 144;
    int ty0 = (tile / 12) * 8, tx0 = (tile % 12) * 8;
    for (int li = tid; li < 6400; li += 256) {
        int c = li / 100, s = li % 100;
        int yy = s / 10, xx = s % 10;
        int gy = ty0 + yy - 1, gx = tx0 + xx - 1;
        float v = 0.f;
        if ((unsigned)gy < 96u && (unsigned)gx < 96u)
            v = x[((n * 64 + c) * 96 + gy) * 96 + gx];
        xl[li] = v;
    }
    for (int e = tid; e < 4096; e += 256) {
        int f = e >> 8, r = e & 255;
        rotT[r * 16 + f] = rot[f * 256 + r];   // rot is (16,4,64)
    }
    __syncthreads();
    int p = tid & 63, og = tid >> 6;
    int row = p >> 3, col = p & 7;
    int ogs = __builtin_amdgcn_readfirstlane(og);   // wave-uniform -> s_load path
    const float* wb = wm + (size_t)ogs * 4 * 576;
    float acc0 = 0.f, acc1 = 0.f, acc2 = 0.f, acc3 = 0.f;
    for (int c = 0; c < 64; ++c) {
        float xp[9];
        int base = c * 100 + row * 10 + col;
        #pragma unroll
        for (int dy = 0; dy < 3; ++dy)
            #pragma unroll
            for (int dx = 0; dx < 3; ++dx)
                xp[dy * 3 + dx] = xl[base + dy * 10 + dx];
        const float* w0 = wb + c * 9;
        #pragma unroll
        for (int u = 0; u < 9; ++u) {
            acc0 += w0[u]        * xp[u];
            acc1 += w0[576 + u]  * xp[u];
            acc2 += w0[1152 + u] * xp[u];
            acc3 += w0[1728 + u] * xp[u];
        }
    }
    int o = ogs * 4;
    float v0 = acc0 + bm[o + 0]; v0 = v0 > 0.f ? v0 : 0.f;
    float v1 = acc1 + bm[o + 1]; v1 = v1 > 0.f ? v1 : 0.f;
    float v2 = acc2 + bm[o + 2]; v2 = v2 > 0.f ? v2 : 0.f;
    float v3 = acc3 + bm[o + 3]; v3 = v3 > 0.f ? v3 : 0.f;
    size_t t = (size_t)n * LL + (ty0 + row) * 96 + tx0 + col;
    float4 vv = make_float4(v0, v1, v2, v3);
    *(float4*)(xe + t * 16 + o) = vv;
    *(float4*)(xsp + p * 20 + o) = vv;
    __syncthreads();
    // ---- codes phase: thread = (pos = tid&63, h = tid>>6) ----
    int pos = tid & 63, h = tid >> 6;
    int prow = pos >> 3, pcol = pos & 7;
    size_t tc = (size_t)n * LL + (ty0 + prow) * 96 + tx0 + pcol;
    float4 q0 = *(float4*)(xsp + pos * 20 + 0);
    float4 q1 = *(float4*)(xsp + pos * 20 + 4);
    float4 q2 = *(float4*)(xsp + pos * 20 + 8);
    float4 q3 = *(float4*)(xsp + pos * 20 + 12);
    if (h == 0) {
        float nn = dot4(q0,q0) + dot4(q1,q1) + dot4(q2,q2) + dot4(q3,q3);
        float s = fmaxf(sqrtf(nn), EPS_N);
        float inv = 1.f / s;
        float4* dst = (float4*)(xn + tc * 16);
        dst[0] = make_float4(q0.x*inv, q0.y*inv, q0.z*inv, q0.w*inv);
        dst[1] = make_float4(q1.x*inv, q1.y*inv, q1.z*inv, q1.w*inv);
        dst[2] = make_float4(q2.x*inv, q2.y*inv, q2.z*inv, q2.w*inv);
        dst[3] = make_float4(q3.x*inv, q3.y*inv, q3.z*inv, q3.w*inv);
    }
    float best = -1e30f; int bi = 0;
    const float* rp = rotT + h * 1024;
    for (int i = 0; i < 64; ++i) {
        const float4* r4 = (const float4*)(rp + i * 16);
        float v = dot4(q0, r4[0]) + dot4(q1, r4[1]) + dot4(q2, r4[2]) + dot4(q3, r4[3]);
        if (v > best) { best = v; bi = i; }   // strict > = first max (jnp.argmax)
    }
    codes[(size_t)n * TOT + h * LL + (tc - (size_t)n * LL)] = (unsigned char)(h * 64 + bi);
}

// ---------------- K2: ye/fe conv bf16 MFMA + fused fc1/relu/fc2 + fused hist -----
// blocks 0..383: conv+fc strip; blocks 384..671: sort histogram.
__global__ __launch_bounds__(256) void k_convbf_fc(
    const float* __restrict__ x, const unsigned short* __restrict__ wpack,
    const float* __restrict__ ba, const float* __restrict__ bfb,
    const unsigned short* __restrict__ w1bf, const float* __restrict__ fc1_b,
    const unsigned short* __restrict__ w2bf, const float* __restrict__ fc2_b,
    unsigned short* __restrict__ yeb, unsigned short* __restrict__ re2b,
    const unsigned char* __restrict__ codes, int* __restrict__ hist)
{
    __shared__ unsigned short xt[3 * 50 * 72];   // input halo strip, ch-inner
    __shared__ unsigned short fet[48 * 72];      // fe tile [pos][ch]
    __shared__ unsigned short hb [48 * 168];     // hid [pos][m pad160]
    __shared__ int lh[256];
    int tid = threadIdx.x;
    if (blockIdx.x >= 384) {   // ---- histogram branch ----
        int b2 = blockIdx.x - 384;
        int n = b2 / NSEG, seg = b2 % NSEG;
        lh[tid] = 0;
        __syncthreads();
        int code = codes[(size_t)n * TOT + seg * 256 + tid];
        atomicAdd(&lh[code], 1);
        __syncthreads();
        hist[((size_t)n * 256 + tid) * NSEG + seg] = lh[tid];
        return;
    }
    int b = blockIdx.x;
    int n = b / 192, rem = b % 192;
    int y = rem >> 1, strip = rem & 1;
    int x0 = strip * 48;
    for (int e = tid; e < 9600; e += 256) {
        int r = e / 3200, r2 = e - r * 3200;
        int c = r2 / 50, j = r2 - c * 50;
        int gy = y - 1 + r, gx = x0 - 1 + j;
        float v = 0.f;
        if ((unsigned)gy < 96u && (unsigned)gx < 96u)
            v = x[((n * 64 + c) * 96 + gy) * 96 + gx];
        xt[(r * 50 + j) * 72 + c] = f2bf(v);
    }
    for (int e = tid; e < 384; e += 256) {       // hb K-pad zero (cols 144..159)
        int r = e >> 3, pq = e & 7;
        *(unsigned int*)(hb + r * 168 + 144 + pq * 2) = 0;
    }
    __syncthreads();
    int wave = tid >> 6, lane = tid & 63;
    int n16 = lane & 15, quad = lane >> 4;
    f32x4 acc[2][3];
    #pragma unroll
    for (int mi = 0; mi < 2; ++mi)
        #pragma unroll
        for (int nt = 0; nt < 3; ++nt) acc[mi][nt] = (f32x4){0.f, 0.f, 0.f, 0.f};
    #pragma unroll
    for (int s = 0; s < 18; ++s) {
        int dydx = s >> 1, half = s & 1;
        int dy = dydx / 3, dxm = dydx - dy * 3;
        bf16x8 B[3];
        #pragma unroll
        for (int nt = 0; nt < 3; ++nt) {
            int j = nt * 16 + n16 + dxm;
            B[nt] = *(bf16x8*)(xt + (dy * 50 + j) * 72 + half * 32 + quad * 8);
        }
        #pragma unroll
        for (int mi = 0; mi < 2; ++mi) {
            int o = (wave * 2 + mi) * 16 + n16;
            bf16x8 A = *(const bf16x8*)(wpack + o * 576 + dydx * 64 + half * 32 + quad * 8);
            #pragma unroll
            for (int nt = 0; nt < 3; ++nt)
                acc[mi][nt] = __builtin_amdgcn_mfma_f32_16x16x32_bf16(A, B[nt], acc[mi][nt], 0, 0, 0);
        }
    }
    #pragma unroll
    for (int mi = 0; mi < 2; ++mi) {
        int mt = wave * 2 + mi;
        int obase = mt * 16 + quad * 4;          // 0..124, multiple of 4
        float4 b4 = (mt < 4) ? *(const float4*)(ba + obase)
                             : *(const float4*)(bfb + obase - 64);
        #pragma unroll
        for (int nt = 0; nt < 3; ++nt) {
            int j = nt * 16 + n16;               // local position 0..47
            unsigned short pk[4];
            float v0 = acc[mi][nt][0] + b4.x; pk[0] = f2bf(v0 > 0.f ? v0 : 0.f);
            float v1 = acc[mi][nt][1] + b4.y; pk[1] = f2bf(v1 > 0.f ? v1 : 0.f);
            float v2 = acc[mi][nt][2] + b4.z; pk[2] = f2bf(v2 > 0.f ? v2 : 0.f);
            float v3 = acc[mi][nt][3] + b4.w; pk[3] = f2bf(v3 > 0.f ? v3 : 0.f);
            if (mt < 4) {
                size_t t = (size_t)n * LL + y * 96 + x0 + j;
                *(uint2*)(yeb + t * 64 + obase) = *(uint2*)pk;
            } else {
                *(uint2*)(fet + j * 72 + (obase - 64)) = *(uint2*)pk;
            }
        }
    }
    __syncthreads();
    size_t R0 = (size_t)n * LL + y * 96 + x0;
    // GEMM1: hid = relu(fe @ w1^T + b1)
    for (int nt = wave; nt < 9; nt += 4) {
        int bn = nt * 16 + n16;
        bf16x8 b0 = *(const bf16x8*)(w1bf + bn * 64 + quad * 8);
        bf16x8 b1 = *(const bf16x8*)(w1bf + bn * 64 + 32 + quad * 8);
        float bb = fc1_b[bn];
        #pragma unroll
        for (int m = 0; m < 3; ++m) {
            int arow = m * 16 + n16;
            bf16x8 a0 = *(bf16x8*)(fet + arow * 72 + quad * 8);
            bf16x8 a1 = *(bf16x8*)(fet + arow * 72 + 32 + quad * 8);
            f32x4 c2 = {0.f, 0.f, 0.f, 0.f};
            c2 = __builtin_amdgcn_mfma_f32_16x16x32_bf16(a0, b0, c2, 0, 0, 0);
            c2 = __builtin_amdgcn_mfma_f32_16x16x32_bf16(a1, b1, c2, 0, 0, 0);
            #pragma unroll
            for (int r = 0; r < 4; ++r) {
                float v = c2[r] + bb;
                hb[(m * 16 + quad * 4 + r) * 168 + bn] = f2bf(v > 0.f ? v : 0.f);
            }
        }
    }
    __syncthreads();
    // GEMM2: re2 = hid @ w2^T + b2 (K=160)
    for (int nt = wave; nt < 9; nt += 4) {
        int bn = nt * 16 + n16;
        bf16x8 wv2[5];
        #pragma unroll
        for (int kk = 0; kk < 5; ++kk)
            wv2[kk] = *(const bf16x8*)(w2bf + bn * 160 + kk * 32 + quad * 8);
        float bb = fc2_b[bn];
        #pragma unroll
        for (int m = 0; m < 3; ++m) {
            int arow = m * 16 + n16;
            f32x4 c2 = {0.f, 0.f, 0.f, 0.f};
            #pragma unroll
            for (int kk = 0; kk < 5; ++kk) {
                bf16x8 a = *(bf16x8*)(hb + arow * 168 + kk * 32 + quad * 8);
                c2 = __builtin_amdgcn_mfma_f32_16x16x32_bf16(a, wv2[kk], c2, 0, 0, 0);
            }
            #pragma unroll
            for (int r = 0; r < 4; ++r)
                re2b[(R0 + m * 16 + quad * 4 + r) * 144 + bn] = f2bf(c2[r] + bb);
        }
    }
}

// ---------------- K3: counting sort scan + place --------------------------------
__global__ void k_scan(int* __restrict__ hist)
{
    __shared__ int sc[256];
    int n = blockIdx.x, bin = threadIdx.x;
    int* hp = hist + ((size_t)n * 256 + bin) * NSEG;
    int4 buf[36];
    int4* hp4 = (int4*)hp;
    #pragma unroll
    for (int q = 0; q < 36; ++q) buf[q] = hp4[q];
    int running = 0;
    #pragma unroll
    for (int q = 0; q < 36; ++q) {
        int t0 = buf[q].x; buf[q].x = running; running += t0;
        int t1 = buf[q].y; buf[q].y = running; running += t1;
        int t2 = buf[q].z; buf[q].z = running; running += t2;
        int t3 = buf[q].w; buf[q].w = running; running += t3;
    }
    sc[bin] = running;
    __syncthreads();
    for (int off = 1; off < 256; off <<= 1) {
        int v = sc[bin];
        int u = (bin >= off) ? sc[bin - off] : 0;
        __syncthreads();
        sc[bin] = v + u;
        __syncthreads();
    }
    int bs = sc[bin] - running;   // exclusive prefix over bins
    #pragma unroll
    for (int q = 0; q < 36; ++q) {
        buf[q].x += bs; buf[q].y += bs; buf[q].z += bs; buf[q].w += bs;
        hp4[q] = buf[q];
    }
}

__global__ __launch_bounds__(256) void k_place(
    const unsigned char* __restrict__ codes, const int* __restrict__ hist,
    int* __restrict__ idx)
{
    __shared__ unsigned char cl[256];
    int b = blockIdx.x, n = b / NSEG, seg = b % NSEG;
    int tid = threadIdx.x;
    int my = codes[(size_t)n * TOT + seg * 256 + tid];
    cl[tid] = (unsigned char)my;
    __syncthreads();
    int rank = 0;
    for (int j = 0; j < tid; ++j) rank += (cl[j] == my);
    int pos = hist[((size_t)n * 256 + my) * NSEG + seg] + rank;
    idx[(size_t)n * TOT + pos] = seg * 256 + tid;
}

// ---------------- K4: bucketed attention, 2-barrier pipelined (R9-proven) --------
// 512 blocks, 2 blocks/CU. DO NOT split keys (R8) or queries (R10): both blow
// the L2 working set (partial-output writeback / 3x staging replication) and
// regress 1.6-1.8x despite higher occupancy.
__global__ __launch_bounds__(256, 2) void k_attn(
    const float* __restrict__ xe, const float* __restrict__ xn,
    const unsigned short* __restrict__ yeb, const unsigned short* __restrict__ re2b,
    const int* __restrict__ idx,
    unsigned short* __restrict__ ret, float* __restrict__ bsc)
{
    __shared__ float xs_s[144 * 16];           // unnormalized query rows (f32)
    __shared__ float xnc[2][48 * 20];          // normalized key tile (f32), dbuf
    __shared__ unsigned short Pb[144 * 72];    // probs bf16 [i][jpad], cols 48..63 = 0
    __shared__ unsigned short yat[2][64 * 72]; // values^T bf16 [c][jpad], dbuf
    __shared__ int   t_arr[432];
    __shared__ float l_sh[144], alpha_sh[144];

    int b = blockIdx.x;
    int n = b >> 8, rem = b & 255;
    int h = rem >> 6, k = rem & 63;
    int tid = threadIdx.x;

    for (int r = tid; r < 432; r += 256) {
        int region = r / 144, i = r - region * 144;
        int dk = (region == 0) ? 0 : (region == 1 ? -1 : 1);
        int ck = (k + dk + 64) & 63;
        t_arr[r] = idx[(size_t)n * TOT + h * LL + ck * CHK + i] - h * LL;
    }
    for (int e = tid; e < 2304; e += 256)              // Pb K-pad zero
        Pb[(e >> 4) * 72 + 48 + (e & 15)] = 0;
    for (int e = tid; e < 2048; e += 256) {            // yat K-pad zero (both bufs)
        int bb2 = e >> 10, r2 = (e >> 4) & 63;
        yat[bb2][r2 * 72 + 48 + (e & 15)] = 0;
    }
    __syncthreads();                                   // t_arr ready
    int si = tid >> 4, tj = tid & 15;          // QK grid: rows si*9.., cols tj*3..
    int lane = tid & 63, wv = tid >> 6;
    int n16 = lane & 15, quad = lane >> 4;     // MFMA lane coords
    for (int e4 = tid; e4 < 576; e4 += 256) {
        int r = e4 >> 2, q = e4 & 3;
        *(float4*)(xs_s + r * 16 + q * 4) =
            *(const float4*)(xe + ((size_t)n * LL + t_arr[r]) * 16 + q * 4);
    }
    // stage tile 0 into buf 0
    {
        #pragma unroll
        for (int q = 0; q < 6; ++q) {
            int e = tid + q * 256;
            int j = e >> 5, c2 = e & 31;
            unsigned int v = *(const unsigned int*)(yeb + ((size_t)n * LL + t_arr[j]) * 64 + c2 * 2);
            yat[0][(c2 * 2 + 0) * 72 + j] = (unsigned short)(v & 0xffff);
            yat[0][(c2 * 2 + 1) * 72 + j] = (unsigned short)(v >> 16);
        }
        if (tid < 192) {
            int j = tid >> 2, q = tid & 3;
            *(float4*)(&xnc[0][j * 20 + q * 4]) =
                *(const float4*)(xn + ((size_t)n * LL + t_arr[j]) * 16 + q * 4);
        }
    }
    // preload tile-0 fc scores
    unsigned short fcvA[27], fcvB[27];
    #pragma unroll
    for (int v = 0; v < 3; ++v) {
        const unsigned short* fp = re2b + ((size_t)n * LL + t_arr[tj * 3 + v]) * 144 + si * 9;
        #pragma unroll
        for (int u = 0; u < 9; ++u) fcvA[v * 9 + u] = fp[u];
    }
    f32x4 acc[9];
    float rm[9], rl[9];
    #pragma unroll
    for (int q = 0; q < 9; ++q) {
        acc[q] = (f32x4){0.f, 0.f, 0.f, 0.f};
        rm[q] = -1e30f; rl[q] = 0.f;
    }
    __syncthreads();                           // tile-0 staging visible

    for (int T = 0; T < 9; ++T) {
        int cur = T & 1, nxt = cur ^ 1;
        int r0 = T * 48;
        // ---- issue next-tile staging loads into registers ----
        unsigned int syv[6];
        float4 sxn;
        if (T < 8) {
            int r1 = r0 + 48;
            #pragma unroll
            for (int q = 0; q < 6; ++q) {
                int e = tid + q * 256;
                int j = e >> 5, c2 = e & 31;
                syv[q] = *(const unsigned int*)(yeb + ((size_t)n * LL + t_arr[r1 + j]) * 64 + c2 * 2);
            }
            if (tid < 192) {
                int j = tid >> 2, q = tid & 3;
                sxn = *(const float4*)(xn + ((size_t)n * LL + t_arr[r1 + j]) * 16 + q * 4);
            }
            #pragma unroll
            for (int v = 0; v < 3; ++v) {
                const unsigned short* fp =
                    re2b + ((size_t)n * LL + t_arr[r1 + tj * 3 + v]) * 144 + si * 9;
                #pragma unroll
                for (int u = 0; u < 9; ++u) fcvB[v * 9 + u] = fp[u];
            }
        }
        // ---- QK + fused online softmax ----
        {
            float4 xnr[3][4];
            #pragma unroll
            for (int v = 0; v < 3; ++v)
                #pragma unroll
                for (int q = 0; q < 4; ++q)
                    xnr[v][q] = *(const float4*)(&xnc[cur][(tj * 3 + v) * 20 + q * 4]);
            #pragma unroll
            for (int u = 0; u < 9; ++u) {
                int i = si * 9 + u;
                const float4* xr = (const float4*)(xs_s + i * 16);
                float4 x0 = xr[0], x1 = xr[1], x2 = xr[2], x3 = xr[3];
                float rv[3];
                #pragma unroll
                for (int v = 0; v < 3; ++v) {
                    float d = dot4(x0, xnr[v][0]) + dot4(x1, xnr[v][1])
                            + dot4(x2, xnr[v][2]) + dot4(x3, xnr[v][3]);
                    rv[v] = bf2f(fcvA[v * 9 + u]) + d;
                }
                float mm = fmaxf(fmaxf(rv[0], rv[1]), rv[2]);
                mm = fmaxf(mm, __shfl_xor(mm, 1, 16));
                mm = fmaxf(mm, __shfl_xor(mm, 2, 16));
                mm = fmaxf(mm, __shfl_xor(mm, 4, 16));
                mm = fmaxf(mm, __shfl_xor(mm, 8, 16));
                float mn = fmaxf(rm[u], mm);
                float a = __expf(rm[u] - mn);
                float s0 = __expf(rv[0] - mn), s1 = __expf(rv[1] - mn), s2 = __expf(rv[2] - mn);
                float ss = s0 + s1 + s2;
                ss += __shfl_xor(ss, 1, 16);
                ss += __shfl_xor(ss, 2, 16);
                ss += __shfl_xor(ss, 4, 16);
                ss += __shfl_xor(ss, 8, 16);
                rl[u] = rl[u] * a + ss;
                rm[u] = mn;
                if (tj == 0) { alpha_sh[i] = a; l_sh[i] = rl[u]; }
                Pb[i * 72 + tj * 3 + 0] = f2bf(s0);
                Pb[i * 72 + tj * 3 + 1] = f2bf(s1);
                Pb[i * 72 + tj * 3 + 2] = f2bf(s2);
            }
        }
        __syncthreads();   // (A) Pb/alpha ready for PV; prev-PV done with yat[nxt]
        // ---- spill staged regs to LDS[nxt]; rotate fcv ----
        if (T < 8) {
            #pragma unroll
            for (int q = 0; q < 6; ++q) {
                int e = tid + q * 256;
                int j = e >> 5, c2 = e & 31;
                yat[nxt][(c2 * 2 + 0) * 72 + j] = (unsigned short)(syv[q] & 0xffff);
                yat[nxt][(c2 * 2 + 1) * 72 + j] = (unsigned short)(syv[q] >> 16);
            }
            if (tid < 192) {
                int j = tid >> 2, q = tid & 3;
                *(float4*)(&xnc[nxt][j * 20 + q * 4]) = sxn;
            }
            #pragma unroll
            for (int q = 0; q < 27; ++q) fcvA[q] = fcvB[q];
        }
        // ---- PV via MFMA: wave wv owns c-tile wv ----
        {
            #pragma unroll
            for (int mt = 0; mt < 9; ++mt) {
                float4 al = *(const float4*)(alpha_sh + mt * 16 + quad * 4);
                acc[mt][0] *= al.x; acc[mt][1] *= al.y;
                acc[mt][2] *= al.z; acc[mt][3] *= al.w;
            }
            #pragma unroll
            for (int kk = 0; kk < 2; ++kk) {
                bf16x8 B = *(bf16x8*)(yat[cur] + (wv * 16 + n16) * 72 + kk * 32 + quad * 8);
                #pragma unroll
                for (int mt = 0; mt < 9; ++mt) {
                    bf16x8 A = *(bf16x8*)(Pb + (mt * 16 + n16) * 72 + kk * 32 + quad * 8);
                    acc[mt] = __builtin_amdgcn_mfma_f32_16x16x32_bf16(A, B, acc[mt], 0, 0, 0);
                }
            }
        }
        __syncthreads();   // (B) Pb free for next QK; xnc/yat[nxt] visible
    }
    // ---- epilogue: bsc from registers; normalize + scatter ret (bf16) ----
    if (tj == 0) {
        #pragma unroll
        for (int u = 0; u < 9; ++u) {
            int i = si * 9 + u;
            bsc[((size_t)n * 4 + h) * LL + t_arr[i]] = rm[u] + __logf(rl[u]);
        }
    }
    size_t obase = ((size_t)n * 4 + h) * LL;
    #pragma unroll
    for (int mt = 0; mt < 9; ++mt) {
        float4 l4 = *(const float4*)(l_sh + mt * 16 + quad * 4);
        int4 t4 = *(const int4*)(t_arr + mt * 16 + quad * 4);
        ret[(obase + t4.x) * 64 + wv * 16 + n16] = f2bf(acc[mt][0] * (1.f / l4.x));
        ret[(obase + t4.y) * 64 + wv * 16 + n16] = f2bf(acc[mt][1] * (1.f / l4.y));
        ret[(obase + t4.z) * 64 + wv * 16 + n16] = f2bf(acc[mt][2] * (1.f / l4.z));
        ret[(obase + t4.w) * 64 + wv * 16 + n16] = f2bf(acc[mt][3] * (1.f / l4.w));
    }
}

// ---------------- K5: softmax over rounds + residual, NCHW output ----------------
__global__ __launch_bounds__(256) void k_final(
    const unsigned short* __restrict__ ret, const float* __restrict__ bsc,
    const float* __restrict__ x, float* __restrict__ out)
{
    __shared__ float pr[4][64];
    __shared__ float accl[64 * 65];
    int b = blockIdx.x, n = b / 144;
    int t0 = (b % 144) * 64;
    int tid = threadIdx.x;
    if (tid < 64) {
        int t = t0 + tid;
        float b0 = bsc[((size_t)n*4 + 0)*LL + t];
        float b1 = bsc[((size_t)n*4 + 1)*LL + t];
        float b2 = bsc[((size_t)n*4 + 2)*LL + t];
        float b3 = bsc[((size_t)n*4 + 3)*LL + t];
        float mx = fmaxf(fmaxf(b0, b1), fmaxf(b2, b3));
        float e0 = __expf(b0-mx), e1 = __expf(b1-mx), e2 = __expf(b2-mx), e3 = __expf(b3-mx);
        float inv = 1.f / (e0 + e1 + e2 + e3);
        pr[0][tid] = e0*inv; pr[1][tid] = e1*inv; pr[2][tid] = e2*inv; pr[3][tid] = e3*inv;
    }
    __syncthreads();
    int cc = tid & 63, tt4 = tid >> 6;
    #pragma unroll
    for (int q = 0; q < 16; ++q) {
        int tt = tt4 + 4*q;
        int t = t0 + tt;
        float v = 0.f;
        #pragma unroll
        for (int h2 = 0; h2 < 4; ++h2)
            v += bf2f(ret[(((size_t)n*4 + h2)*LL + t)*64 + cc]) * pr[h2][tt];
        accl[cc*65 + tt] = v;
    }
    __syncthreads();
    int tt = tid & 63, c4 = tid >> 6;
    #pragma unroll
    for (int q = 0; q < 16; ++q) {
        int ch = c4 + 4*q;
        size_t o = ((size_t)n*64 + ch)*LL + t0 + tt;
        out[o] = accl[ch*65 + tt] + x[o];   // RES_SCALE = 1.0
    }
}

// ---------------- launcher ----------------
extern "C" void kernel_launch(void* const* d_in, const int* in_sizes, int n_in,
                              void* d_out, int out_size, void* d_ws, size_t ws_size,
                              hipStream_t stream)
{
    const float* x    = (const float*)d_in[0];
    const float* rot  = (const float*)d_in[1];
    const float* wm   = (const float*)d_in[2];
    const float* bm   = (const float*)d_in[3];
    const float* wa   = (const float*)d_in[4];
    const float* ba   = (const float*)d_in[5];
    const float* wf   = (const float*)d_in[6];
    const float* bf   = (const float*)d_in[7];
    const float* fc1w = (const float*)d_in[8];
    const float* fc1b = (const float*)d_in[9];
    const float* fc2w = (const float*)d_in[10];
    const float* fc2b = (const float*)d_in[11];
    float* out = (float*)d_out;

    char* ws = (char*)d_ws;
    float* xe            = (float*)(ws + 0);                  // 2*9216*16 f32
    unsigned short* yeb  = (unsigned short*)(ws + 1179648);   // 2*9216*64 bf16
    float* xn            = (float*)(ws + 3538944);            // 2*9216*16 f32
    unsigned short* re2b = (unsigned short*)(ws + 4718592);   // 2*9216*144 bf16
    unsigned short* w1bf = (unsigned short*)(ws + 10027008);  // 144*64 bf16
    unsigned short* w2bf = (unsigned short*)(ws + 10045440);  // 144*160 bf16
    unsigned short* wpak = (unsigned short*)(ws + 10091520);  // 128*576 bf16
    unsigned char* codes = (unsigned char*)(ws + 10238976);   // 2*36864 u8
    int* hist            = (int*)(ws + 10312704);             // 2*256*144 i32
    int* idxb            = (int*)(ws + 10607616);             // 2*36864 i32
    unsigned short* retb = (unsigned short*)(ws + 10902528);  // 2*4*9216*64 bf16
    float* bscb          = (float*)(ws + 20339712);           // 2*4*9216 f32 (end 20,634,624)

    k_front    <<<576, 256, 0, stream>>>(x, wm, bm, rot, xe, xn, codes,
                                         fc1w, fc2w, wa, wf, w1bf, w2bf, wpak);
    k_convbf_fc<<<672, 256, 0, stream>>>(x, wpak, ba, bf, w1bf, fc1b, w2bf, fc2b,
                                         yeb, re2b, codes, hist);
    k_scan     <<<2,   256, 0, stream>>>(hist);
    k_place    <<<288, 256, 0, stream>>>(codes, hist, idxb);
    k_attn     <<<512, 256, 0, stream>>>(xe, xn, yeb, re2b, idxb, retb, bscb);
    k_final    <<<288, 256, 0, stream>>>(retb, bscb, x, out);
}

// Round 12
// 242.312 us; speedup vs baseline: 1.2372x; 1.0328x over previous
//
#include <hip/hip_runtime.h>
#include <hip/hip_bf16.h>

#define LL 9216            // 96*96
#define TOT 36864          // 4*LL
#define CHK 144
#define NSEG 144
#define EPS_N 5e-5f

typedef __bf16 bf16x8 __attribute__((ext_vector_type(8)));
typedef float f32x4 __attribute__((ext_vector_type(4)));

__device__ __forceinline__ float dot4(float4 a, float4 b) {
    return a.x*b.x + a.y*b.y + a.z*b.z + a.w*b.w;
}
__device__ __forceinline__ unsigned short f2bf(float f) {
    __hip_bfloat16 h = __float2bfloat16(f);
    return *reinterpret_cast<unsigned short*>(&h);
}
__device__ __forceinline__ float bf2f(unsigned short u) {
    return __uint_as_float(((unsigned int)u) << 16);
}

// ---------------- K1: xe conv + LSH codes + bf16 xeb/xnb + weight prep -----------
// blocks 0..287: conv 8x8 tile + codes; blocks 288..575: weight prep. 46 KB LDS.
__global__ __launch_bounds__(256) void k_front(
    const float* __restrict__ x, const float* __restrict__ wm,
    const float* __restrict__ bm, const float* __restrict__ rot,
    unsigned short* __restrict__ xeb, unsigned short* __restrict__ xnb,
    unsigned char* __restrict__ codes,
    const float* __restrict__ fc1w, const float* __restrict__ fc2w,
    const float* __restrict__ wa, const float* __restrict__ wf,
    unsigned short* __restrict__ w1bf, unsigned short* __restrict__ w2bf,
    unsigned short* __restrict__ wpack)
{
    int tid = threadIdx.x;
    if (blockIdx.x >= 288) {   // ---- weight prep ----
        int i = (blockIdx.x - 288) * 256 + tid;
        if (i < 144 * 64) w1bf[i] = f2bf(fc1w[i]);
        if (i < 144 * 160) {
            int r = i / 160, c = i - r * 160;
            w2bf[i] = (c < 144) ? f2bf(fc2w[r * 144 + c]) : 0;
        }
        if (i < 128 * 576) {
            int o = i / 576, kk = i - o * 576;
            int dydx = kk >> 6, c = kk & 63;
            const float* src = (o < 64) ? wa : wf;
            wpack[i] = f2bf(src[(o & 63) * 576 + c * 9 + dydx]);
        }
        return;
    }
    __shared__ float xl[6400];       // [64][10][10] halo tile (25.6 KB)
    __shared__ float rotT[4096];     // [h*64+i][16]          (16 KB)
    __shared__ float xsp[64 * 20];   // [pos][ch pad20]       (5 KB)
    int b = blockIdx.x;
    int n = b / 144, tile = b % 144;
    int ty0 = (tile / 12) * 8, tx0 = (tile % 12) * 8;
    for (int li = tid; li < 6400; li += 256) {
        int c = li / 100, s = li % 100;
        int yy = s / 10, xx = s % 10;
        int gy = ty0 + yy - 1, gx = tx0 + xx - 1;
        float v = 0.f;
        if ((unsigned)gy < 96u && (unsigned)gx < 96u)
            v = x[((n * 64 + c) * 96 + gy) * 96 + gx];
        xl[li] = v;
    }
    for (int e = tid; e < 4096; e += 256) {
        int f = e >> 8, r = e & 255;
        rotT[r * 16 + f] = rot[f * 256 + r];   // rot is (16,4,64)
    }
    __syncthreads();
    int p = tid & 63, og = tid >> 6;
    int row = p >> 3, col = p & 7;
    int ogs = __builtin_amdgcn_readfirstlane(og);   // wave-uniform -> s_load path
    const float* wb = wm + (size_t)ogs * 4 * 576;
    float acc0 = 0.f, acc1 = 0.f, acc2 = 0.f, acc3 = 0.f;
    for (int c = 0; c < 64; ++c) {
        float xp[9];
        int base = c * 100 + row * 10 + col;
        #pragma unroll
        for (int dy = 0; dy < 3; ++dy)
            #pragma unroll
            for (int dx = 0; dx < 3; ++dx)
                xp[dy * 3 + dx] = xl[base + dy * 10 + dx];
        const float* w0 = wb + c * 9;
        #pragma unroll
        for (int u = 0; u < 9; ++u) {
            acc0 += w0[u]        * xp[u];
            acc1 += w0[576 + u]  * xp[u];
            acc2 += w0[1152 + u] * xp[u];
            acc3 += w0[1728 + u] * xp[u];
        }
    }
    int o = ogs * 4;
    float v0 = acc0 + bm[o + 0]; v0 = v0 > 0.f ? v0 : 0.f;
    float v1 = acc1 + bm[o + 1]; v1 = v1 > 0.f ? v1 : 0.f;
    float v2 = acc2 + bm[o + 2]; v2 = v2 > 0.f ? v2 : 0.f;
    float v3 = acc3 + bm[o + 3]; v3 = v3 > 0.f ? v3 : 0.f;
    size_t t = (size_t)n * LL + (ty0 + row) * 96 + tx0 + col;
    unsigned short pk[4] = {f2bf(v0), f2bf(v1), f2bf(v2), f2bf(v3)};
    *(uint2*)(xeb + t * 16 + o) = *(uint2*)pk;
    *(float4*)(xsp + p * 20 + o) = make_float4(v0, v1, v2, v3);
    __syncthreads();
    // ---- codes phase: thread = (pos = tid&63, h = tid>>6) ----
    int pos = tid & 63, h = tid >> 6;
    int prow = pos >> 3, pcol = pos & 7;
    size_t tc = (size_t)n * LL + (ty0 + prow) * 96 + tx0 + pcol;
    float4 q0 = *(float4*)(xsp + pos * 20 + 0);
    float4 q1 = *(float4*)(xsp + pos * 20 + 4);
    float4 q2 = *(float4*)(xsp + pos * 20 + 8);
    float4 q3 = *(float4*)(xsp + pos * 20 + 12);
    if (h == 0) {
        float nn = dot4(q0,q0) + dot4(q1,q1) + dot4(q2,q2) + dot4(q3,q3);
        float s = fmaxf(sqrtf(nn), EPS_N);
        float inv = 1.f / s;
        unsigned short pn[16];
        pn[0]=f2bf(q0.x*inv);  pn[1]=f2bf(q0.y*inv);  pn[2]=f2bf(q0.z*inv);  pn[3]=f2bf(q0.w*inv);
        pn[4]=f2bf(q1.x*inv);  pn[5]=f2bf(q1.y*inv);  pn[6]=f2bf(q1.z*inv);  pn[7]=f2bf(q1.w*inv);
        pn[8]=f2bf(q2.x*inv);  pn[9]=f2bf(q2.y*inv);  pn[10]=f2bf(q2.z*inv); pn[11]=f2bf(q2.w*inv);
        pn[12]=f2bf(q3.x*inv); pn[13]=f2bf(q3.y*inv); pn[14]=f2bf(q3.z*inv); pn[15]=f2bf(q3.w*inv);
        *(uint4*)(xnb + tc * 16)     = ((uint4*)pn)[0];
        *(uint4*)(xnb + tc * 16 + 8) = ((uint4*)pn)[1];
    }
    float best = -1e30f; int bi = 0;
    const float* rp = rotT + h * 1024;
    for (int i = 0; i < 64; ++i) {
        const float4* r4 = (const float4*)(rp + i * 16);
        float v = dot4(q0, r4[0]) + dot4(q1, r4[1]) + dot4(q2, r4[2]) + dot4(q3, r4[3]);
        if (v > best) { best = v; bi = i; }   // strict > = first max (jnp.argmax)
    }
    codes[(size_t)n * TOT + h * LL + (tc - (size_t)n * LL)] = (unsigned char)(h * 64 + bi);
}

// ---------------- K2: ye/fe conv bf16 MFMA + fused fc1/relu/fc2 + fused hist -----
__global__ __launch_bounds__(256) void k_convbf_fc(
    const float* __restrict__ x, const unsigned short* __restrict__ wpack,
    const float* __restrict__ ba, const float* __restrict__ bfb,
    const unsigned short* __restrict__ w1bf, const float* __restrict__ fc1_b,
    const unsigned short* __restrict__ w2bf, const float* __restrict__ fc2_b,
    unsigned short* __restrict__ yeb, unsigned short* __restrict__ re2b,
    const unsigned char* __restrict__ codes, int* __restrict__ hist)
{
    __shared__ unsigned short xt[3 * 50 * 72];   // input halo strip, ch-inner
    __shared__ unsigned short fet[48 * 72];      // fe tile [pos][ch]
    __shared__ unsigned short hb [48 * 168];     // hid [pos][m pad160]
    __shared__ int lh[256];
    int tid = threadIdx.x;
    if (blockIdx.x >= 384) {   // ---- histogram branch ----
        int b2 = blockIdx.x - 384;
        int n = b2 / NSEG, seg = b2 % NSEG;
        lh[tid] = 0;
        __syncthreads();
        int code = codes[(size_t)n * TOT + seg * 256 + tid];
        atomicAdd(&lh[code], 1);
        __syncthreads();
        hist[((size_t)n * 256 + tid) * NSEG + seg] = lh[tid];
        return;
    }
    int b = blockIdx.x;
    int n = b / 192, rem = b % 192;
    int y = rem >> 1, strip = rem & 1;
    int x0 = strip * 48;
    for (int e = tid; e < 9600; e += 256) {
        int r = e / 3200, r2 = e - r * 3200;
        int c = r2 / 50, j = r2 - c * 50;
        int gy = y - 1 + r, gx = x0 - 1 + j;
        float v = 0.f;
        if ((unsigned)gy < 96u && (unsigned)gx < 96u)
            v = x[((n * 64 + c) * 96 + gy) * 96 + gx];
        xt[(r * 50 + j) * 72 + c] = f2bf(v);
    }
    for (int e = tid; e < 384; e += 256) {       // hb K-pad zero (cols 144..159)
        int r = e >> 3, pq = e & 7;
        *(unsigned int*)(hb + r * 168 + 144 + pq * 2) = 0;
    }
    __syncthreads();
    int wave = tid >> 6, lane = tid & 63;
    int n16 = lane & 15, quad = lane >> 4;
    f32x4 acc[2][3];
    #pragma unroll
    for (int mi = 0; mi < 2; ++mi)
        #pragma unroll
        for (int nt = 0; nt < 3; ++nt) acc[mi][nt] = (f32x4){0.f, 0.f, 0.f, 0.f};
    #pragma unroll
    for (int s = 0; s < 18; ++s) {
        int dydx = s >> 1, half = s & 1;
        int dy = dydx / 3, dxm = dydx - dy * 3;
        bf16x8 B[3];
        #pragma unroll
        for (int nt = 0; nt < 3; ++nt) {
            int j = nt * 16 + n16 + dxm;
            B[nt] = *(bf16x8*)(xt + (dy * 50 + j) * 72 + half * 32 + quad * 8);
        }
        #pragma unroll
        for (int mi = 0; mi < 2; ++mi) {
            int o = (wave * 2 + mi) * 16 + n16;
            bf16x8 A = *(const bf16x8*)(wpack + o * 576 + dydx * 64 + half * 32 + quad * 8);
            #pragma unroll
            for (int nt = 0; nt < 3; ++nt)
                acc[mi][nt] = __builtin_amdgcn_mfma_f32_16x16x32_bf16(A, B[nt], acc[mi][nt], 0, 0, 0);
        }
    }
    #pragma unroll
    for (int mi = 0; mi < 2; ++mi) {
        int mt = wave * 2 + mi;
        int obase = mt * 16 + quad * 4;          // 0..124, multiple of 4
        float4 b4 = (mt < 4) ? *(const float4*)(ba + obase)
                             : *(const float4*)(bfb + obase - 64);
        #pragma unroll
        for (int nt = 0; nt < 3; ++nt) {
            int j = nt * 16 + n16;               // local position 0..47
            unsigned short pk[4];
            float v0 = acc[mi][nt][0] + b4.x; pk[0] = f2bf(v0 > 0.f ? v0 : 0.f);
            float v1 = acc[mi][nt][1] + b4.y; pk[1] = f2bf(v1 > 0.f ? v1 : 0.f);
            float v2 = acc[mi][nt][2] + b4.z; pk[2] = f2bf(v2 > 0.f ? v2 : 0.f);
            float v3 = acc[mi][nt][3] + b4.w; pk[3] = f2bf(v3 > 0.f ? v3 : 0.f);
            if (mt < 4) {
                size_t t = (size_t)n * LL + y * 96 + x0 + j;
                *(uint2*)(yeb + t * 64 + obase) = *(uint2*)pk;
            } else {
                *(uint2*)(fet + j * 72 + (obase - 64)) = *(uint2*)pk;
            }
        }
    }
    __syncthreads();
    size_t R0 = (size_t)n * LL + y * 96 + x0;
    // GEMM1: hid = relu(fe @ w1^T + b1)
    for (int nt = wave; nt < 9; nt += 4) {
        int bn = nt * 16 + n16;
        bf16x8 b0 = *(const bf16x8*)(w1bf + bn * 64 + quad * 8);
        bf16x8 b1 = *(const bf16x8*)(w1bf + bn * 64 + 32 + quad * 8);
        float bb = fc1_b[bn];
        #pragma unroll
        for (int m = 0; m < 3; ++m) {
            int arow = m * 16 + n16;
            bf16x8 a0 = *(bf16x8*)(fet + arow * 72 + quad * 8);
            bf16x8 a1 = *(bf16x8*)(fet + arow * 72 + 32 + quad * 8);
            f32x4 c2 = {0.f, 0.f, 0.f, 0.f};
            c2 = __builtin_amdgcn_mfma_f32_16x16x32_bf16(a0, b0, c2, 0, 0, 0);
            c2 = __builtin_amdgcn_mfma_f32_16x16x32_bf16(a1, b1, c2, 0, 0, 0);
            #pragma unroll
            for (int r = 0; r < 4; ++r) {
                float v = c2[r] + bb;
                hb[(m * 16 + quad * 4 + r) * 168 + bn] = f2bf(v > 0.f ? v : 0.f);
            }
        }
    }
    __syncthreads();
    // GEMM2: re2 = hid @ w2^T + b2 (K=160)
    for (int nt = wave; nt < 9; nt += 4) {
        int bn = nt * 16 + n16;
        bf16x8 wv2[5];
        #pragma unroll
        for (int kk = 0; kk < 5; ++kk)
            wv2[kk] = *(const bf16x8*)(w2bf + bn * 160 + kk * 32 + quad * 8);
        float bb = fc2_b[bn];
        #pragma unroll
        for (int m = 0; m < 3; ++m) {
            int arow = m * 16 + n16;
            f32x4 c2 = {0.f, 0.f, 0.f, 0.f};
            #pragma unroll
            for (int kk = 0; kk < 5; ++kk) {
                bf16x8 a = *(bf16x8*)(hb + arow * 168 + kk * 32 + quad * 8);
                c2 = __builtin_amdgcn_mfma_f32_16x16x32_bf16(a, wv2[kk], c2, 0, 0, 0);
            }
            #pragma unroll
            for (int r = 0; r < 4; ++r)
                re2b[(R0 + m * 16 + quad * 4 + r) * 144 + bn] = f2bf(c2[r] + bb);
        }
    }
}

// ---------------- K3: counting sort scan + place --------------------------------
__global__ void k_scan(int* __restrict__ hist)
{
    __shared__ int sc[256];
    int n = blockIdx.x, bin = threadIdx.x;
    int* hp = hist + ((size_t)n * 256 + bin) * NSEG;
    int4 buf[36];
    int4* hp4 = (int4*)hp;
    #pragma unroll
    for (int q = 0; q < 36; ++q) buf[q] = hp4[q];
    int running = 0;
    #pragma unroll
    for (int q = 0; q < 36; ++q) {
        int t0 = buf[q].x; buf[q].x = running; running += t0;
        int t1 = buf[q].y; buf[q].y = running; running += t1;
        int t2 = buf[q].z; buf[q].z = running; running += t2;
        int t3 = buf[q].w; buf[q].w = running; running += t3;
    }
    sc[bin] = running;
    __syncthreads();
    for (int off = 1; off < 256; off <<= 1) {
        int v = sc[bin];
        int u = (bin >= off) ? sc[bin - off] : 0;
        __syncthreads();
        sc[bin] = v + u;
        __syncthreads();
    }
    int bs = sc[bin] - running;   // exclusive prefix over bins
    #pragma unroll
    for (int q = 0; q < 36; ++q) {
        buf[q].x += bs; buf[q].y += bs; buf[q].z += bs; buf[q].w += bs;
        hp4[q] = buf[q];
    }
}

__global__ __launch_bounds__(256) void k_place(
    const unsigned char* __restrict__ codes, const int* __restrict__ hist,
    int* __restrict__ idx)
{
    __shared__ unsigned char cl[256];
    int b = blockIdx.x, n = b / NSEG, seg = b % NSEG;
    int tid = threadIdx.x;
    int my = codes[(size_t)n * TOT + seg * 256 + tid];
    cl[tid] = (unsigned char)my;
    __syncthreads();
    int rank = 0;
    for (int j = 0; j < tid; ++j) rank += (cl[j] == my);
    int pos = hist[((size_t)n * 256 + my) * NSEG + seg] + rank;
    idx[(size_t)n * TOT + pos] = seg * 256 + tid;
}

// ---------------- K4: bucketed attention — QK via MFMA + fused softmax + PV ------
// 512 blocks, 2/CU (key/query splits proven harmful: R8/R10). QK uses the same
// 16x16x32_bf16 fragment convention as k_fc/PV (HW-verified in this codebase).
// fc scores enter as the MFMA C-operand initializer. K=32 with k16..31 zeroed.
__global__ __launch_bounds__(256, 2) void k_attn(
    const unsigned short* __restrict__ xeb, const unsigned short* __restrict__ xnb,
    const unsigned short* __restrict__ yeb, const unsigned short* __restrict__ re2b,
    const int* __restrict__ idx,
    unsigned short* __restrict__ ret, float* __restrict__ bsc)
{
    __shared__ unsigned short xsA[144 * 40];     // queries A-layout [i][k], k16..31=0
    __shared__ unsigned short xnB[2][48 * 40];   // keys  B-layout [j][k], k16..31=0, dbuf
    __shared__ unsigned short Pb[144 * 72];      // probs bf16 [i][jpad], 48..63=0
    __shared__ unsigned short yat[2][64 * 72];   // values^T bf16 [c][jpad], dbuf
    __shared__ unsigned short t_arr[432];
    __shared__ float l_sh[144], alpha_sh[144];

    int b = blockIdx.x;
    int n = b >> 8, rem = b & 255;
    int h = rem >> 6, k = rem & 63;
    int tid = threadIdx.x;
    int lane = tid & 63, wv = tid >> 6;
    int n16 = lane & 15, quad = lane >> 4;
    int nmt = (wv == 0) ? 3 : 2;                 // mt tiles owned: {wv, wv+4, wv+8?}

    for (int r = tid; r < 432; r += 256) {
        int region = r / 144, i = r - region * 144;
        int dk = (region == 0) ? 0 : (region == 1 ? -1 : 1);
        int ck = (k + dk + 64) & 63;
        t_arr[r] = (unsigned short)(idx[(size_t)n * TOT + h * LL + ck * CHK + i] - h * LL);
    }
    for (int e = tid; e < 2304; e += 256)              // Pb K-pad zero
        Pb[(e >> 4) * 72 + 48 + (e & 15)] = 0;
    for (int e = tid; e < 2048; e += 256) {            // yat K-pad zero (both bufs)
        int bb2 = e >> 10, r2 = (e >> 4) & 63;
        yat[bb2][r2 * 72 + 48 + (e & 15)] = 0;
    }
    for (int e = tid; e < 2304; e += 256)              // xsA K-pad zero
        xsA[(e >> 4) * 40 + 16 + (e & 15)] = 0;
    for (int e = tid; e < 1536; e += 256) {            // xnB K-pad zero (both bufs)
        int bb2 = e / 768, r2 = (e >> 4) % 48;
        xnB[bb2][r2 * 40 + 16 + (e & 15)] = 0;
    }
    __syncthreads();                                   // t_arr ready
    // stage queries into A-layout (once)
    for (int e = tid; e < 288; e += 256) {
        int row = e >> 1, half = e & 1;
        *(uint4*)(xsA + row * 40 + half * 8) =
            *(const uint4*)(xeb + ((size_t)n * LL + t_arr[row]) * 16 + half * 8);
    }
    // stage tile 0 into buf 0
    {
        #pragma unroll
        for (int q = 0; q < 6; ++q) {
            int e = tid + q * 256;
            int j = e >> 5, c2 = e & 31;
            unsigned int v = *(const unsigned int*)(yeb + ((size_t)n * LL + t_arr[j]) * 64 + c2 * 2);
            yat[0][(c2 * 2 + 0) * 72 + j] = (unsigned short)(v & 0xffff);
            yat[0][(c2 * 2 + 1) * 72 + j] = (unsigned short)(v >> 16);
        }
        if (tid < 96) {
            int j = tid >> 1, half = tid & 1;
            *(uint4*)(&xnB[0][j * 40 + half * 8]) =
                *(const uint4*)(xnb + ((size_t)n * LL + t_arr[j]) * 16 + half * 8);
        }
    }
    // preload tile-0 fc scores (C-operand init): fcv[nt][mi] = re2[t_col][row0..row0+3]
    ushort4 fcvA[3][3], fcvB[3][3];
    #pragma unroll
    for (int nt = 0; nt < 3; ++nt) {
        int col = nt * 16 + n16;
        #pragma unroll
        for (int mi = 0; mi < 3; ++mi)
            if (mi < nmt)
                fcvA[nt][mi] = *(const ushort4*)(re2b
                    + ((size_t)n * LL + t_arr[col]) * 144 + (wv + mi * 4) * 16 + quad * 4);
    }
    f32x4 acc[9];
    float rm[3][4], rl[3][4];
    #pragma unroll
    for (int q = 0; q < 9; ++q) acc[q] = (f32x4){0.f, 0.f, 0.f, 0.f};
    #pragma unroll
    for (int mi = 0; mi < 3; ++mi)
        #pragma unroll
        for (int r = 0; r < 4; ++r) { rm[mi][r] = -1e30f; rl[mi][r] = 0.f; }
    __syncthreads();                           // staging visible
    // preload static A-frags (queries)
    bf16x8 afrag[3];
    #pragma unroll
    for (int mi = 0; mi < 3; ++mi)
        if (mi < nmt)
            afrag[mi] = *(bf16x8*)(xsA + ((wv + mi * 4) * 16 + n16) * 40 + quad * 8);

    for (int T = 0; T < 9; ++T) {
        int cur = T & 1, nxt = cur ^ 1;
        int r0 = T * 48;
        // ---- issue next-tile staging loads into registers ----
        unsigned int syv[6];
        uint4 sxn;
        if (T < 8) {
            int r1 = r0 + 48;
            #pragma unroll
            for (int q = 0; q < 6; ++q) {
                int e = tid + q * 256;
                int j = e >> 5, c2 = e & 31;
                syv[q] = *(const unsigned int*)(yeb + ((size_t)n * LL + t_arr[r1 + j]) * 64 + c2 * 2);
            }
            if (tid < 96) {
                int j = tid >> 1, half = tid & 1;
                sxn = *(const uint4*)(xnb + ((size_t)n * LL + t_arr[r1 + j]) * 16 + half * 8);
            }
            #pragma unroll
            for (int nt = 0; nt < 3; ++nt) {
                int col = nt * 16 + n16;
                #pragma unroll
                for (int mi = 0; mi < 3; ++mi)
                    if (mi < nmt)
                        fcvB[nt][mi] = *(const ushort4*)(re2b
                            + ((size_t)n * LL + t_arr[r1 + col]) * 144 + (wv + mi * 4) * 16 + quad * 4);
            }
        }
        // ---- QK via MFMA (C init = fc scores) + fused online softmax ----
        {
            bf16x8 bfrag[3];
            #pragma unroll
            for (int nt = 0; nt < 3; ++nt)
                bfrag[nt] = *(bf16x8*)(xnB[cur] + (nt * 16 + n16) * 40 + quad * 8);
            #pragma unroll
            for (int mi = 0; mi < 3; ++mi) {
                if (mi >= nmt) continue;
                int rowb = (wv + mi * 4) * 16 + quad * 4;
                ushort4 f0 = fcvA[0][mi], f1 = fcvA[1][mi], f2v = fcvA[2][mi];
                f32x4 c0 = {bf2f(f0.x), bf2f(f0.y), bf2f(f0.z), bf2f(f0.w)};
                f32x4 c1 = {bf2f(f1.x), bf2f(f1.y), bf2f(f1.z), bf2f(f1.w)};
                f32x4 c2 = {bf2f(f2v.x), bf2f(f2v.y), bf2f(f2v.z), bf2f(f2v.w)};
                c0 = __builtin_amdgcn_mfma_f32_16x16x32_bf16(afrag[mi], bfrag[0], c0, 0, 0, 0);
                c1 = __builtin_amdgcn_mfma_f32_16x16x32_bf16(afrag[mi], bfrag[1], c1, 0, 0, 0);
                c2 = __builtin_amdgcn_mfma_f32_16x16x32_bf16(afrag[mi], bfrag[2], c2, 0, 0, 0);
                #pragma unroll
                for (int r = 0; r < 4; ++r) {
                    float v0 = c0[r], v1 = c1[r], v2 = c2[r];
                    float mm = fmaxf(fmaxf(v0, v1), v2);
                    mm = fmaxf(mm, __shfl_xor(mm, 1, 16));
                    mm = fmaxf(mm, __shfl_xor(mm, 2, 16));
                    mm = fmaxf(mm, __shfl_xor(mm, 4, 16));
                    mm = fmaxf(mm, __shfl_xor(mm, 8, 16));
                    float mn = fmaxf(rm[mi][r], mm);
                    float a = __expf(rm[mi][r] - mn);
                    float s0 = __expf(v0 - mn), s1 = __expf(v1 - mn), s2 = __expf(v2 - mn);
                    float ss = s0 + s1 + s2;
                    ss += __shfl_xor(ss, 1, 16);
                    ss += __shfl_xor(ss, 2, 16);
                    ss += __shfl_xor(ss, 4, 16);
                    ss += __shfl_xor(ss, 8, 16);
                    rl[mi][r] = rl[mi][r] * a + ss;
                    rm[mi][r] = mn;
                    if (n16 == 0) { alpha_sh[rowb + r] = a; l_sh[rowb + r] = rl[mi][r]; }
                    Pb[(rowb + r) * 72 +      n16] = f2bf(s0);
                    Pb[(rowb + r) * 72 + 16 + n16] = f2bf(s1);
                    Pb[(rowb + r) * 72 + 32 + n16] = f2bf(s2);
                }
            }
        }
        __syncthreads();   // (A) Pb/alpha ready for PV; prev-PV done with yat[nxt]
        // ---- spill staged regs to LDS[nxt]; rotate fcv ----
        if (T < 8) {
            #pragma unroll
            for (int q = 0; q < 6; ++q) {
                int e = tid + q * 256;
                int j = e >> 5, c2 = e & 31;
                yat[nxt][(c2 * 2 + 0) * 72 + j] = (unsigned short)(syv[q] & 0xffff);
                yat[nxt][(c2 * 2 + 1) * 72 + j] = (unsigned short)(syv[q] >> 16);
            }
            if (tid < 96) {
                int j = tid >> 1, half = tid & 1;
                *(uint4*)(&xnB[nxt][j * 40 + half * 8]) = sxn;
            }
            #pragma unroll
            for (int nt = 0; nt < 3; ++nt)
                #pragma unroll
                for (int mi = 0; mi < 3; ++mi)
                    if (mi < nmt) fcvA[nt][mi] = fcvB[nt][mi];
        }
        // ---- PV via MFMA: wave wv owns c-tile wv ----
        {
            #pragma unroll
            for (int mt = 0; mt < 9; ++mt) {
                float4 al = *(const float4*)(alpha_sh + mt * 16 + quad * 4);
                acc[mt][0] *= al.x; acc[mt][1] *= al.y;
                acc[mt][2] *= al.z; acc[mt][3] *= al.w;
            }
            #pragma unroll
            for (int kk = 0; kk < 2; ++kk) {
                bf16x8 B = *(bf16x8*)(yat[cur] + (wv * 16 + n16) * 72 + kk * 32 + quad * 8);
                #pragma unroll
                for (int mt = 0; mt < 9; ++mt) {
                    bf16x8 A = *(bf16x8*)(Pb + (mt * 16 + n16) * 72 + kk * 32 + quad * 8);
                    acc[mt] = __builtin_amdgcn_mfma_f32_16x16x32_bf16(A, B, acc[mt], 0, 0, 0);
                }
            }
        }
        __syncthreads();   // (B) Pb free for next QK; xnB/yat[nxt] visible
    }
    // ---- epilogue: bsc from registers; normalize + scatter ret (bf16) ----
    if (n16 == 0) {
        #pragma unroll
        for (int mi = 0; mi < 3; ++mi) {
            if (mi >= nmt) continue;
            int rowb = (wv + mi * 4) * 16 + quad * 4;
            #pragma unroll
            for (int r = 0; r < 4; ++r)
                bsc[((size_t)n * 4 + h) * LL + t_arr[rowb + r]] = rm[mi][r] + __logf(rl[mi][r]);
        }
    }
    size_t obase = ((size_t)n * 4 + h) * LL;
    #pragma unroll
    for (int mt = 0; mt < 9; ++mt) {
        float4 l4 = *(const float4*)(l_sh + mt * 16 + quad * 4);
        ushort4 t4 = *(const ushort4*)(t_arr + mt * 16 + quad * 4);
        ret[(obase + t4.x) * 64 + wv * 16 + n16] = f2bf(acc[mt][0] * (1.f / l4.x));
        ret[(obase + t4.y) * 64 + wv * 16 + n16] = f2bf(acc[mt][1] * (1.f / l4.y));
        ret[(obase + t4.z) * 64 + wv * 16 + n16] = f2bf(acc[mt][2] * (1.f / l4.z));
        ret[(obase + t4.w) * 64 + wv * 16 + n16] = f2bf(acc[mt][3] * (1.f / l4.w));
    }
}

// ---------------- K5: softmax over rounds + residual, NCHW output ----------------
__global__ __launch_bounds__(256) void k_final(
    const unsigned short* __restrict__ ret, const float* __restrict__ bsc,
    const float* __restrict__ x, float* __restrict__ out)
{
    __shared__ float pr[4][64];
    __shared__ float accl[64 * 65];
    int b = blockIdx.x, n = b / 144;
    int t0 = (b % 144) * 64;
    int tid = threadIdx.x;
    if (tid < 64) {
        int t = t0 + tid;
        float b0 = bsc[((size_t)n*4 + 0)*LL + t];
        float b1 = bsc[((size_t)n*4 + 1)*LL + t];
        float b2 = bsc[((size_t)n*4 + 2)*LL + t];
        float b3 = bsc[((size_t)n*4 + 3)*LL + t];
        float mx = fmaxf(fmaxf(b0, b1), fmaxf(b2, b3));
        float e0 = __expf(b0-mx), e1 = __expf(b1-mx), e2 = __expf(b2-mx), e3 = __expf(b3-mx);
        float inv = 1.f / (e0 + e1 + e2 + e3);
        pr[0][tid] = e0*inv; pr[1][tid] = e1*inv; pr[2][tid] = e2*inv; pr[3][tid] = e3*inv;
    }
    __syncthreads();
    int cc = tid & 63, tt4 = tid >> 6;
    #pragma unroll
    for (int q = 0; q < 16; ++q) {
        int tt = tt4 + 4*q;
        int t = t0 + tt;
        float v = 0.f;
        #pragma unroll
        for (int h2 = 0; h2 < 4; ++h2)
            v += bf2f(ret[(((size_t)n*4 + h2)*LL + t)*64 + cc]) * pr[h2][tt];
        accl[cc*65 + tt] = v;
    }
    __syncthreads();
    int tt = tid & 63, c4 = tid >> 6;
    #pragma unroll
    for (int q = 0; q < 16; ++q) {
        int ch = c4 + 4*q;
        size_t o = ((size_t)n*64 + ch)*LL + t0 + tt;
        out[o] = accl[ch*65 + tt] + x[o];   // RES_SCALE = 1.0
    }
}

// ---------------- launcher ----------------
extern "C" void kernel_launch(void* const* d_in, const int* in_sizes, int n_in,
                              void* d_out, int out_size, void* d_ws, size_t ws_size,
                              hipStream_t stream)
{
    const float* x    = (const float*)d_in[0];
    const float* rot  = (const float*)d_in[1];
    const float* wm   = (const float*)d_in[2];
    const float* bm   = (const float*)d_in[3];
    const float* wa   = (const float*)d_in[4];
    const float* ba   = (const float*)d_in[5];
    const float* wf   = (const float*)d_in[6];
    const float* bf   = (const float*)d_in[7];
    const float* fc1w = (const float*)d_in[8];
    const float* fc1b = (const float*)d_in[9];
    const float* fc2w = (const float*)d_in[10];
    const float* fc2b = (const float*)d_in[11];
    float* out = (float*)d_out;

    char* ws = (char*)d_ws;
    unsigned short* xeb  = (unsigned short*)(ws + 0);         // 2*9216*16 bf16
    unsigned short* yeb  = (unsigned short*)(ws + 589824);    // 2*9216*64 bf16
    unsigned short* xnb  = (unsigned short*)(ws + 2949120);   // 2*9216*16 bf16
    unsigned short* re2b = (unsigned short*)(ws + 3538944);   // 2*9216*144 bf16
    unsigned short* w1bf = (unsigned short*)(ws + 8847360);   // 144*64 bf16
    unsigned short* w2bf = (unsigned short*)(ws + 8865792);   // 144*160 bf16
    unsigned short* wpak = (unsigned short*)(ws + 8911872);   // 128*576 bf16
    unsigned char* codes = (unsigned char*)(ws + 9059328);    // 2*36864 u8
    int* hist            = (int*)(ws + 9133056);              // 2*256*144 i32
    int* idxb            = (int*)(ws + 9427968);              // 2*36864 i32
    unsigned short* retb = (unsigned short*)(ws + 9575424);   // 2*4*9216*64 bf16
    float* bscb          = (float*)(ws + 19012608);           // 2*4*9216 f32 (end 19,307,520)

    k_front    <<<576, 256, 0, stream>>>(x, wm, bm, rot, xeb, xnb, codes,
                                         fc1w, fc2w, wa, wf, w1bf, w2bf, wpak);
    k_convbf_fc<<<672, 256, 0, stream>>>(x, wpak, ba, bf, w1bf, fc1b, w2bf, fc2b,
                                         yeb, re2b, codes, hist);
    k_scan     <<<2,   256, 0, stream>>>(hist);
    k_place    <<<288, 256, 0, stream>>>(codes, hist, idxb);
    k_attn     <<<512, 256, 0, stream>>>(xeb, xnb, yeb, re2b, idxb, retb, bscb);
    k_final    <<<288, 256, 0, stream>>>(retb, bscb, x, out);
}